// Round 3
// baseline (373.875 us; speedup 1.0000x reference)
//
#include <hip/hip_runtime.h>
#include <math.h>

#define BB 8
#define SS 2048
#define DDIM 128
#define NTOK (BB * SS)   // 16384
#define ATB_SPLIT 16

using bf16x8 = __attribute__((ext_vector_type(8))) short;
using f32x4  = __attribute__((ext_vector_type(4))) float;

__device__ __forceinline__ float gelu_exact(float v) {
    return 0.5f * v * (1.0f + erff(v * 0.70710678118654752f));
}

// fp32 -> bf16 (round to nearest even), returns raw bits
__device__ __forceinline__ unsigned short f2b(float f) {
    unsigned int u = __float_as_uint(f);
    u += 0x7FFFu + ((u >> 16) & 1u);
    return (unsigned short)(u >> 16);
}

// ---------------------------------------------------------------------------
// bf16 MFMA GEMM: C[m*ldc+n] = epi( sum_k A[m][k]*W[n][k] + bias[n] )
// A: (M,K) bf16 row-major. W: (N,K) bf16 row-major. 128x128 block tile,
// 4 waves each 64x64 via 4x4 frags of 16x16x32 MFMA. M%128==0, N%128==0,
// K%32==0. epi: act=1 -> exact gelu; scale[m]; res (fp32); C fp32 and/or
// Cb bf16 outputs (either may be null).
// ---------------------------------------------------------------------------
__global__ __launch_bounds__(256) void gemm_bf16(
    const unsigned short* __restrict__ A, const unsigned short* __restrict__ W,
    const float* __restrict__ bias, const float* __restrict__ res,
    const float* __restrict__ scale,
    float* __restrict__ C, unsigned short* __restrict__ Cb,
    int M, int N, int K, int ldc, int act)
{
    __shared__ unsigned short As[128 * 32];
    __shared__ unsigned short Bs[128 * 32];
    const int tid = threadIdx.x;
    const int m0 = blockIdx.x * 128, n0 = blockIdx.y * 128;
    const int wv = tid >> 6, lane = tid & 63;
    const int wm = (wv >> 1) * 64, wn = (wv & 1) * 64;
    const int ln = lane & 15, q = lane >> 4;

    f32x4 acc[4][4] = {};

    for (int k0 = 0; k0 < K; k0 += 32) {
        #pragma unroll
        for (int it = 0; it < 2; ++it) {
            int idx = tid + it * 256;
            int r = idx >> 2, c = (idx & 3) * 8;
            *(uint4*)&As[r * 32 + c] = *(const uint4*)&A[(size_t)(m0 + r) * K + k0 + c];
            *(uint4*)&Bs[r * 32 + c] = *(const uint4*)&W[(size_t)(n0 + r) * K + k0 + c];
        }
        __syncthreads();
        bf16x8 a[4], b[4];
        #pragma unroll
        for (int i = 0; i < 4; ++i)
            a[i] = *(const bf16x8*)&As[(wm + i * 16 + ln) * 32 + q * 8];
        #pragma unroll
        for (int j = 0; j < 4; ++j)
            b[j] = *(const bf16x8*)&Bs[(wn + j * 16 + ln) * 32 + q * 8];
        #pragma unroll
        for (int i = 0; i < 4; ++i)
            #pragma unroll
            for (int j = 0; j < 4; ++j)
                acc[i][j] = __builtin_amdgcn_mfma_f32_16x16x32_bf16(a[i], b[j], acc[i][j], 0, 0, 0);
        __syncthreads();
    }

    #pragma unroll
    for (int i = 0; i < 4; ++i) {
        #pragma unroll
        for (int r = 0; r < 4; ++r) {
            int row = m0 + wm + i * 16 + q * 4 + r;
            float sc = (scale != nullptr) ? scale[row] : 1.0f;
            #pragma unroll
            for (int j = 0; j < 4; ++j) {
                int col = n0 + wn + j * 16 + ln;
                float v = acc[i][j][r] + bias[col];
                if (act) v = gelu_exact(v);
                v *= sc;
                size_t off = (size_t)row * ldc + col;
                if (res != nullptr) v += res[off];
                if (C != nullptr) C[off] = v;
                if (Cb != nullptr) Cb[off] = f2b(v);
            }
        }
    }
}

// ---------------------------------------------------------------------------
// Convert x, spatial, temporal (fp32) -> bf16. 4 elems/thread.
// ---------------------------------------------------------------------------
__global__ __launch_bounds__(256) void convert3_kernel(
    const float* __restrict__ x, const float* __restrict__ sp, const float* __restrict__ tp,
    unsigned short* __restrict__ xb, unsigned short* __restrict__ spb, unsigned short* __restrict__ tpb)
{
    const int per = NTOK * 128 / 4;   // 524288 float4s per tensor
    int i = blockIdx.x * 256 + threadIdx.x;
    int t = i / per, r = i % per;
    const float* s = (t == 0) ? x : (t == 1) ? sp : tp;
    unsigned short* d = (t == 0) ? xb : (t == 1) ? spb : tpb;
    float4 v = *(const float4*)&s[(size_t)r * 4];
    ushort4 o = {f2b(v.x), f2b(v.y), f2b(v.z), f2b(v.w)};
    *(ushort4*)&d[(size_t)r * 4] = o;
}

// ---------------------------------------------------------------------------
// Convert all 8 weight matrices fp32 -> packed bf16 buffer.
// Offsets: lw_in 0 | lw_out 49152 | ffn1 65536 | ffn2 131072 | spat 196608 |
//          temp 212992 | int_in 229376 | int_out 278528 | total 294912
// ---------------------------------------------------------------------------
__global__ __launch_bounds__(256) void convertW_kernel(
    const float* __restrict__ w0, const float* __restrict__ w1,
    const float* __restrict__ w2, const float* __restrict__ w3,
    const float* __restrict__ w4, const float* __restrict__ w5,
    const float* __restrict__ w6, const float* __restrict__ w7,
    unsigned short* __restrict__ dst)
{
    int i = blockIdx.x * 256 + threadIdx.x;   // 0..294911
    const float* s; int base;
    if      (i < 49152)  { s = w0; base = 0; }
    else if (i < 65536)  { s = w1; base = 49152; }
    else if (i < 131072) { s = w2; base = 65536; }
    else if (i < 196608) { s = w3; base = 131072; }
    else if (i < 212992) { s = w4; base = 196608; }
    else if (i < 229376) { s = w5; base = 212992; }
    else if (i < 278528) { s = w6; base = 229376; }
    else                 { s = w7; base = 278528; }
    dst[i] = f2b(s[i - base]);
}

// ---------------------------------------------------------------------------
// LayerNorm rows of 128 (in-place fp32) + optional bf16 copy.
// ---------------------------------------------------------------------------
__global__ __launch_bounds__(128) void ln_kernel(
    float* __restrict__ x, unsigned short* __restrict__ xb,
    const float* __restrict__ g, const float* __restrict__ b)
{
    const int row = blockIdx.x, tid = threadIdx.x;
    __shared__ float cross[2][2];
    float v = x[(size_t)row * 128 + tid];
    float s = v, qq = v * v;
    #pragma unroll
    for (int o = 32; o > 0; o >>= 1) {
        s += __shfl_xor(s, o, 64);
        qq += __shfl_xor(qq, o, 64);
    }
    int wid = tid >> 6;
    if ((tid & 63) == 0) { cross[0][wid] = s; cross[1][wid] = qq; }
    __syncthreads();
    float mu  = (cross[0][0] + cross[0][1]) * (1.0f / 128.0f);
    float ex2 = (cross[1][0] + cross[1][1]) * (1.0f / 128.0f);
    float var = ex2 - mu * mu;
    float o = (v - mu) * rsqrtf(var + 1e-5f) * g[tid] + b[tid];
    x[(size_t)row * 128 + tid] = o;
    if (xb != nullptr) xb[(size_t)row * 128 + tid] = f2b(o);
}

// ---------------------------------------------------------------------------
// Cosine normalize rows of 128 (fp32 -> fp32)
// ---------------------------------------------------------------------------
__global__ __launch_bounds__(128) void cosnorm_kernel(
    const float* __restrict__ in, float* __restrict__ out)
{
    const int row = blockIdx.x, tid = threadIdx.x;
    __shared__ float cross[2];
    float v = in[(size_t)row * 128 + tid];
    float q = v * v;
    #pragma unroll
    for (int o = 32; o > 0; o >>= 1) q += __shfl_xor(q, o, 64);
    if ((tid & 63) == 0) cross[tid >> 6] = q;
    __syncthreads();
    float n = fmaxf(sqrtf(cross[0] + cross[1]), 1e-8f);
    out[(size_t)row * 128 + tid] = v / n;
}

// ---------------------------------------------------------------------------
// Windowed causal attention. qkv fp32 (NTOK,384)=[q|k|v]; out bf16 (NTOK,128).
// ---------------------------------------------------------------------------
__global__ __launch_bounds__(64) void win_attn_kernel(
    const float* __restrict__ qkv, unsigned short* __restrict__ out)
{
    const int w = blockIdx.x, h = blockIdx.y, l = threadIdx.x;
    __shared__ float Ks[64][16];
    __shared__ float Vs[64][16];
    const float* base = qkv + (size_t)(w * 64 + l) * 384 + h * 16;
    #pragma unroll
    for (int c4 = 0; c4 < 16; c4 += 4) {
        *(float4*)&Ks[l][c4] = *(const float4*)(base + 128 + c4);
        *(float4*)&Vs[l][c4] = *(const float4*)(base + 256 + c4);
    }
    float q[16];
    #pragma unroll
    for (int c = 0; c < 16; ++c) q[c] = base[c];
    __syncthreads();

    float m = -1e30f, ssum = 0.0f;
    float o[16] = {};
    for (int j = 0; j <= l; ++j) {
        float s = 0.0f;
        #pragma unroll
        for (int c = 0; c < 16; ++c) s = fmaf(q[c], Ks[j][c], s);
        s *= 0.25f;
        float mnew = fmaxf(m, s);
        float corr = expf(m - mnew);
        float p = expf(s - mnew);
        ssum = ssum * corr + p;
        #pragma unroll
        for (int c = 0; c < 16; ++c) o[c] = o[c] * corr + p * Vs[j][c];
        m = mnew;
    }
    float inv = 1.0f / ssum;
    unsigned short* op = out + (size_t)(w * 64 + l) * 128 + h * 16;
    #pragma unroll
    for (int c = 0; c < 16; ++c) op[c] = f2b(o[c] * inv);
}

// ---------------------------------------------------------------------------
// Split-K A^T B per batch (fp32): part[(b*SPLIT+chunk)*16384 + d*128 + e]
// ---------------------------------------------------------------------------
__global__ __launch_bounds__(256) void atb_split_kernel(
    const float* __restrict__ sn, const float* __restrict__ tn,
    float* __restrict__ part)
{
    const int b = blockIdx.z / ATB_SPLIT;
    const int chunk = blockIdx.z % ATB_SPLIT;
    const int d0 = blockIdx.x * 64, e0 = blockIdx.y * 64;
    __shared__ float Ss[32][68];
    __shared__ float Ts[32][68];
    const int tid = threadIdx.x;
    const int tx = tid % 16, ty = tid / 16;
    const float* sb = sn + (size_t)b * SS * 128;
    const float* tb = tn + (size_t)b * SS * 128;
    const int jbase = chunk * (SS / ATB_SPLIT);
    float acc[4][4] = {};
    for (int j0 = jbase; j0 < jbase + SS / ATB_SPLIT; j0 += 32) {
        #pragma unroll
        for (int it = 0; it < 2; ++it) {
            int idx = tid + it * 256;
            int r = idx / 16, c4 = (idx % 16) * 4;
            *(float4*)&Ss[r][c4] = *(const float4*)&sb[(size_t)(j0 + r) * 128 + d0 + c4];
            *(float4*)&Ts[r][c4] = *(const float4*)&tb[(size_t)(j0 + r) * 128 + e0 + c4];
        }
        __syncthreads();
        #pragma unroll
        for (int kk = 0; kk < 32; ++kk) {
            float4 af = *(const float4*)&Ss[kk][ty * 4];
            float4 wf = *(const float4*)&Ts[kk][tx * 4];
            float a[4] = {af.x, af.y, af.z, af.w};
            float w[4] = {wf.x, wf.y, wf.z, wf.w};
            #pragma unroll
            for (int i = 0; i < 4; ++i)
                #pragma unroll
                for (int j = 0; j < 4; ++j)
                    acc[i][j] = fmaf(a[i], w[j], acc[i][j]);
        }
        __syncthreads();
    }
    float* pp = part + (size_t)(b * ATB_SPLIT + chunk) * 16384;
    #pragma unroll
    for (int i = 0; i < 4; ++i) {
        float4 ov = {acc[i][0], acc[i][1], acc[i][2], acc[i][3]};
        *(float4*)&pp[(size_t)(d0 + ty * 4 + i) * 128 + e0 + tx * 4] = ov;
    }
}

__global__ __launch_bounds__(256) void atb_reduce_kernel(
    const float* __restrict__ part, float* __restrict__ Mb)
{
    int i = blockIdx.x * 256 + threadIdx.x;
    int b = i / 16384, pos = i % 16384;
    const float* pp = part + (size_t)b * ATB_SPLIT * 16384 + pos;
    float s = 0.0f;
    #pragma unroll
    for (int c = 0; c < ATB_SPLIT; ++c) s += pp[(size_t)c * 16384];
    Mb[i] = s;
}

// ---------------------------------------------------------------------------
// sim[row] = (1/S) * sn_row^T M_b tn_row
// ---------------------------------------------------------------------------
__global__ __launch_bounds__(256) void sim_kernel(
    const float* __restrict__ sn, const float* __restrict__ tn,
    const float* __restrict__ Mb, float* __restrict__ sim)
{
    const int row0 = blockIdx.x * 16;
    const int b = row0 / SS;
    __shared__ float sn_s[16][128];
    __shared__ float tn_s[16][128];
    __shared__ float red[16][128];
    const int tid = threadIdx.x;
    for (int i4 = tid; i4 < 512; i4 += 256) {
        int r = i4 / 32, c4 = (i4 % 32) * 4;
        *(float4*)&sn_s[r][c4] = *(const float4*)&sn[(size_t)(row0 + r) * 128 + c4];
        *(float4*)&tn_s[r][c4] = *(const float4*)&tn[(size_t)(row0 + r) * 128 + c4];
    }
    __syncthreads();
    const int e = tid % 128, half = tid / 128;
    float acc[8] = {};
    const float* Mp = Mb + (size_t)b * 16384;
    for (int d = 0; d < 128; ++d) {
        float mv = Mp[(size_t)d * 128 + e];
        #pragma unroll
        for (int r = 0; r < 8; ++r) acc[r] = fmaf(sn_s[half * 8 + r][d], mv, acc[r]);
    }
    #pragma unroll
    for (int r = 0; r < 8; ++r) red[half * 8 + r][e] = acc[r] * tn_s[half * 8 + r][e];
    __syncthreads();
    if (tid < 16) {
        float s = 0.0f;
        for (int e2 = 0; e2 < 128; ++e2) s += red[tid][e2];
        sim[row0 + tid] = s * (1.0f / (float)SS);
    }
}

// ---------------------------------------------------------------------------
// Interaction attention (len=8 over batch, heads=8, hd=16). qkv fp32, AO bf16.
// ---------------------------------------------------------------------------
__global__ __launch_bounds__(64) void inter_attn_kernel(
    const float* __restrict__ qkvi, unsigned short* __restrict__ AO)
{
    const int s = blockIdx.x, tid = threadIdx.x;
    __shared__ float Q[8][128];
    __shared__ float Km[8][128];
    __shared__ float Vm[8][128];
    __shared__ float P[8][8][8];
    for (int i4 = tid; i4 < 768; i4 += 64) {
        int mat = i4 / 256, rem = i4 % 256;
        int i = rem / 32, c4 = (rem % 32) * 4;
        float4 v = *(const float4*)(qkvi + (size_t)(i * SS + s) * 384 + mat * 128 + c4);
        float* dst = (mat == 0) ? &Q[i][c4] : (mat == 1) ? &Km[i][c4] : &Vm[i][c4];
        *(float4*)dst = v;
    }
    __syncthreads();
    for (int idx = tid; idx < 512; idx += 64) {
        int h = idx >> 6, i = (idx >> 3) & 7, j = idx & 7;
        float sum = 0.0f;
        #pragma unroll
        for (int c = 0; c < 16; ++c) sum = fmaf(Q[i][h * 16 + c], Km[j][h * 16 + c], sum);
        P[h][i][j] = sum * 0.25f;
    }
    __syncthreads();
    {
        int h = tid >> 3, i = tid & 7;
        float m = -1e30f;
        #pragma unroll
        for (int j = 0; j < 8; ++j) m = fmaxf(m, P[h][i][j]);
        float pj[8], ssum = 0.0f;
        #pragma unroll
        for (int j = 0; j < 8; ++j) { pj[j] = expf(P[h][i][j] - m); ssum += pj[j]; }
        float inv = 1.0f / ssum;
        #pragma unroll
        for (int j = 0; j < 8; ++j) P[h][i][j] = pj[j] * inv;
    }
    __syncthreads();
    for (int o = tid; o < 1024; o += 64) {
        int i = o >> 7, c = o & 127, h = c >> 4;
        float sum = 0.0f;
        #pragma unroll
        for (int j = 0; j < 8; ++j) sum = fmaf(P[h][i][j], Vm[j][c], sum);
        AO[(size_t)(i * SS + s) * 128 + c] = f2b(sum);
    }
}

// ---------------------------------------------------------------------------
extern "C" void kernel_launch(void* const* d_in, const int* in_sizes, int n_in,
                              void* d_out, int out_size, void* d_ws, size_t ws_size,
                              hipStream_t stream)
{
    const float* x        = (const float*)d_in[0];
    const float* spatial  = (const float*)d_in[1];
    const float* temporal = (const float*)d_in[2];
    const float* lw_in_w  = (const float*)d_in[3];
    const float* lw_in_b  = (const float*)d_in[4];
    const float* lw_out_w = (const float*)d_in[5];
    const float* lw_out_b = (const float*)d_in[6];
    const float* spat_w   = (const float*)d_in[7];
    const float* spat_b   = (const float*)d_in[8];
    const float* temp_w   = (const float*)d_in[9];
    const float* temp_b   = (const float*)d_in[10];
    const float* int_in_w = (const float*)d_in[11];
    const float* int_in_b = (const float*)d_in[12];
    const float* int_out_w= (const float*)d_in[13];
    const float* int_out_b= (const float*)d_in[14];
    const float* ffn_w1   = (const float*)d_in[15];
    const float* ffn_b1   = (const float*)d_in[16];
    const float* ffn_w2   = (const float*)d_in[17];
    const float* ffn_b2   = (const float*)d_in[18];
    const float* ln1_g    = (const float*)d_in[19];
    const float* ln1_b    = (const float*)d_in[20];
    const float* ln2_g    = (const float*)d_in[21];
    const float* ln2_b    = (const float*)d_in[22];
    float* out = (float*)d_out;

    // ---- workspace layout (bytes), total ~85.1 MB ----
    char* base = (char*)d_ws;
    float*          qkv   = (float*)(base + 0);           // 25,165,824 B
    unsigned short* attnb = (unsigned short*)(base + 25165824);  // 4,194,304
    float*          x1    = (float*)(base + 29360128);    // 8,388,608
    unsigned short* x1b   = (unsigned short*)(base + 37748736);  // 4,194,304
    unsigned short* hb    = (unsigned short*)(base + 41943040);  // 16,777,216
    float*          x2    = (float*)(base + 58720256);    // 8,388,608
    unsigned short* seb   = (unsigned short*)(base + 67108864);  // 4,194,304
    float*          Mb    = (float*)(base + 71303168);    // 524,288
    float*          simb  = (float*)(base + 71827456);    // 65,536
    unsigned short* xb    = (unsigned short*)(base + 71892992);  // 4,194,304
    unsigned short* spb   = (unsigned short*)(base + 76087296);  // 4,194,304
    unsigned short* tpb   = (unsigned short*)(base + 80281600);  // 4,194,304
    unsigned short* Wb    = (unsigned short*)(base + 84475904);  // 589,824
    // aliases inside qkv region (dead between win_attn and int-qkv):
    float* se   = (float*)(base + 0);          // steps 8-10
    float* te   = (float*)(base + 8388608);    // steps 9-10
    float* part = (float*)(base + 16777216);   // step 11
    // aliases for fp32 cos-norm results:
    float* sn = x1;                   // x1 dead after FFN2 residual
    float* tn = (float*)hb;           // h dead after FFN2
    // Wb offsets (bf16 elements)
    unsigned short* Wb_lwin  = Wb + 0;
    unsigned short* Wb_lwout = Wb + 49152;
    unsigned short* Wb_ffn1  = Wb + 65536;
    unsigned short* Wb_ffn2  = Wb + 131072;
    unsigned short* Wb_spat  = Wb + 196608;
    unsigned short* Wb_temp  = Wb + 212992;
    unsigned short* Wb_intin = Wb + 229376;    // q: +0 (16384), kv: +16384 (32768)
    unsigned short* Wb_intout= Wb + 278528;

    // --- 0. conversions ---
    convert3_kernel<<<6144, 256, 0, stream>>>(x, spatial, temporal, xb, spb, tpb);
    convertW_kernel<<<1152, 256, 0, stream>>>(lw_in_w, lw_out_w, ffn_w1, ffn_w2,
                                              spat_w, temp_w, int_in_w, int_out_w, Wb);

    // --- 1. window QKV (fp32 out for attention) ---
    gemm_bf16<<<dim3(NTOK / 128, 3), 256, 0, stream>>>(
        xb, Wb_lwin, lw_in_b, nullptr, nullptr, qkv, nullptr, NTOK, 384, 128, 384, 0);
    // --- 2. windowed causal attention -> bf16 ---
    win_attn_kernel<<<dim3(256, 8), 64, 0, stream>>>(qkv, attnb);
    // --- 3. out proj + residual(x) -> x1 fp32 ---
    gemm_bf16<<<dim3(NTOK / 128, 1), 256, 0, stream>>>(
        attnb, Wb_lwout, lw_out_b, x, nullptr, x1, nullptr, NTOK, 128, 128, 128, 0);
    // --- 4. LN1 (in place) + bf16 copy ---
    ln_kernel<<<NTOK, 128, 0, stream>>>(x1, x1b, ln1_g, ln1_b);
    // --- 5. FFN1 + GELU -> h bf16 only ---
    gemm_bf16<<<dim3(NTOK / 128, 4), 256, 0, stream>>>(
        x1b, Wb_ffn1, ffn_b1, nullptr, nullptr, nullptr, hb, NTOK, 512, 128, 512, 1);
    // --- 6. FFN2 + residual(x1) -> x2 fp32 ---
    gemm_bf16<<<dim3(NTOK / 128, 1), 256, 0, stream>>>(
        hb, Wb_ffn2, ffn_b2, x1, nullptr, x2, nullptr, NTOK, 128, 512, 128, 0);
    // --- 7. LN2 (in place) ---
    ln_kernel<<<NTOK, 128, 0, stream>>>(x2, nullptr, ln2_g, ln2_b);
    // --- 8/9. se, te projections (fp32 + bf16 copies) ---
    gemm_bf16<<<dim3(NTOK / 128, 1), 256, 0, stream>>>(
        spb, Wb_spat, spat_b, nullptr, nullptr, se, seb, NTOK, 128, 128, 128, 0);
    gemm_bf16<<<dim3(NTOK / 128, 1), 256, 0, stream>>>(
        tpb, Wb_temp, temp_b, nullptr, nullptr, te, x1b /*teb alias*/, NTOK, 128, 128, 128, 0);
    // --- 10. cosine norms ---
    cosnorm_kernel<<<NTOK, 128, 0, stream>>>(se, sn);
    cosnorm_kernel<<<NTOK, 128, 0, stream>>>(te, tn);
    // --- 11. M_b = sn^T tn per batch (split-K, partials alias qkv tail) ---
    atb_split_kernel<<<dim3(2, 2, 8 * ATB_SPLIT), 256, 0, stream>>>(sn, tn, part);
    atb_reduce_kernel<<<512, 256, 0, stream>>>(part, Mb);
    // --- 12. sim ---
    sim_kernel<<<NTOK / 16, 256, 0, stream>>>(sn, tn, Mb, simb);
    // --- 13. interaction QKV: q from seb, k/v from teb(x1b) -> qkv fp32 ---
    gemm_bf16<<<dim3(NTOK / 128, 1), 256, 0, stream>>>(
        seb, Wb_intin, int_in_b, nullptr, nullptr, qkv, nullptr, NTOK, 128, 128, 384, 0);
    gemm_bf16<<<dim3(NTOK / 128, 2), 256, 0, stream>>>(
        x1b, Wb_intin + 16384, int_in_b + 128, nullptr, nullptr, qkv + 128, nullptr,
        NTOK, 256, 128, 384, 0);
    // --- 14. interaction attention -> bf16 (reuse attnb) ---
    inter_attn_kernel<<<SS, 64, 0, stream>>>(qkv, attnb);
    // --- 15. out proj * sim + x2 -> d_out ---
    gemm_bf16<<<dim3(NTOK / 128, 1), 256, 0, stream>>>(
        attnb, Wb_intout, int_out_b, x2, simb, out, nullptr, NTOK, 128, 128, 128, 0);
}

// Round 4
// 273.115 us; speedup vs baseline: 1.3689x; 1.3689x over previous
//
#include <hip/hip_runtime.h>
#include <math.h>

#define BB 8
#define SS 2048
#define NTOK (BB * SS)   // 16384
#define ATB_SPLIT 16

using bf16x8 = __attribute__((ext_vector_type(8))) short;
using f32x4  = __attribute__((ext_vector_type(4))) float;

__device__ __forceinline__ float gelu_exact(float v) {
    return 0.5f * v * (1.0f + erff(v * 0.70710678118654752f));
}
__device__ __forceinline__ unsigned short f2b(float f) {
    unsigned int u = __float_as_uint(f);
    u += 0x7FFFu + ((u >> 16) & 1u);
    return (unsigned short)(u >> 16);
}
__device__ __forceinline__ float b2f(unsigned short u) {
    return __uint_as_float((unsigned int)u << 16);
}

// ---------------------------------------------------------------------------
// Single-stage K=128 bf16 MFMA GEMM. A:(M,128) bf16, W:(N,128) bf16.
// Block: 64 rows x 128 cols (blockIdx.y*128 col offset). One barrier total.
// mode 0: v=(acc+bias)*scale(+res) -> C fp32 / Cb bf16
// mode 2: v=acc+bias+res -> LayerNorm(128, g,b) -> C fp32 + Cb bf16 (ldc=128)
// mode 3: v=acc+bias -> Cb=bf16(v), C=v/max(||row||,1e-8)        (ldc=128)
// ---------------------------------------------------------------------------
__global__ __launch_bounds__(256) void gemm_k128(
    const unsigned short* __restrict__ A, const unsigned short* __restrict__ W,
    const float* __restrict__ bias, const float* __restrict__ res,
    const float* __restrict__ scale,
    const float* __restrict__ lng, const float* __restrict__ lnb,
    float* __restrict__ C, unsigned short* __restrict__ Cb,
    int ldc, int mode)
{
    __shared__ unsigned short As[64 * 136];   // row pad 136 -> 2-way banks
    __shared__ unsigned short Ws[128 * 136];
    __shared__ float red[2][64][2];
    const int tid = threadIdx.x;
    const int m0 = blockIdx.x * 64, n0 = blockIdx.y * 128;

    const uint4* A4 = (const uint4*)(A + (size_t)m0 * 128);
    #pragma unroll
    for (int t = 0; t < 4; ++t) {
        int idx = tid + t * 256;            // 1024 uint4 (64 rows x 16)
        int r = idx >> 4, c = idx & 15;
        *(uint4*)&As[r * 136 + c * 8] = A4[r * 16 + c];
    }
    const uint4* W4 = (const uint4*)(W + (size_t)n0 * 128);
    #pragma unroll
    for (int t = 0; t < 8; ++t) {
        int idx = tid + t * 256;            // 2048 uint4 (128 rows x 16)
        int r = idx >> 4, c = idx & 15;
        *(uint4*)&Ws[r * 136 + c * 8] = W4[r * 16 + c];
    }
    __syncthreads();

    const int wv = tid >> 6, lane = tid & 63, ln = lane & 15, q = lane >> 4;
    const int wm = (wv >> 1) * 32, wn = (wv & 1) * 64;
    f32x4 acc[2][4] = {};
    #pragma unroll
    for (int kf = 0; kf < 4; ++kf) {
        bf16x8 a[2], b[4];
        #pragma unroll
        for (int fm = 0; fm < 2; ++fm)
            a[fm] = *(const bf16x8*)&As[(wm + fm * 16 + ln) * 136 + kf * 32 + q * 8];
        #pragma unroll
        for (int fn = 0; fn < 4; ++fn)
            b[fn] = *(const bf16x8*)&Ws[(wn + fn * 16 + ln) * 136 + kf * 32 + q * 8];
        #pragma unroll
        for (int fm = 0; fm < 2; ++fm)
            #pragma unroll
            for (int fn = 0; fn < 4; ++fn)
                acc[fm][fn] = __builtin_amdgcn_mfma_f32_16x16x32_bf16(a[fm], b[fn], acc[fm][fn], 0, 0, 0);
    }

    float bcol[4];
    #pragma unroll
    for (int fn = 0; fn < 4; ++fn) bcol[fn] = bias[n0 + wn + fn * 16 + ln];

    if (mode == 0) {
        #pragma unroll
        for (int fm = 0; fm < 2; ++fm)
            #pragma unroll
            for (int r = 0; r < 4; ++r) {
                int row = m0 + wm + fm * 16 + q * 4 + r;
                float sc = (scale != nullptr) ? scale[row] : 1.0f;
                #pragma unroll
                for (int fn = 0; fn < 4; ++fn) {
                    int col = n0 + wn + fn * 16 + ln;
                    float vv = (acc[fm][fn][r] + bcol[fn]) * sc;
                    size_t off = (size_t)row * ldc + col;
                    if (res != nullptr) vv += res[off];
                    if (C != nullptr) C[off] = vv;
                    if (Cb != nullptr) Cb[off] = f2b(vv);
                }
            }
    } else {
        #pragma unroll
        for (int fm = 0; fm < 2; ++fm)
            #pragma unroll
            for (int r = 0; r < 4; ++r) {
                int rl = wm + fm * 16 + q * 4 + r;
                int row = m0 + rl;
                float s1 = 0.0f, s2 = 0.0f;
                #pragma unroll
                for (int fn = 0; fn < 4; ++fn) {
                    int col = wn + fn * 16 + ln;
                    float vv = acc[fm][fn][r] + bcol[fn];
                    if (mode == 2) vv += res[(size_t)row * 128 + col];
                    acc[fm][fn][r] = vv;
                    s1 += vv; s2 += vv * vv;
                }
                #pragma unroll
                for (int off = 1; off < 16; off <<= 1) {
                    s1 += __shfl_xor(s1, off, 64);
                    s2 += __shfl_xor(s2, off, 64);
                }
                if (ln == 0) { red[0][rl][wv & 1] = s1; red[1][rl][wv & 1] = s2; }
            }
        __syncthreads();
        #pragma unroll
        for (int fm = 0; fm < 2; ++fm)
            #pragma unroll
            for (int r = 0; r < 4; ++r) {
                int rl = wm + fm * 16 + q * 4 + r;
                int row = m0 + rl;
                float o2 = red[1][rl][0] + red[1][rl][1];
                if (mode == 2) {
                    float mu = (red[0][rl][0] + red[0][rl][1]) * (1.0f / 128.0f);
                    float var = o2 * (1.0f / 128.0f) - mu * mu;
                    float rs = rsqrtf(var + 1e-5f);
                    #pragma unroll
                    for (int fn = 0; fn < 4; ++fn) {
                        int col = wn + fn * 16 + ln;
                        float o = (acc[fm][fn][r] - mu) * rs * lng[col] + lnb[col];
                        C[(size_t)row * 128 + col] = o;
                        Cb[(size_t)row * 128 + col] = f2b(o);
                    }
                } else {
                    float inv = 1.0f / fmaxf(sqrtf(o2), 1e-8f);
                    #pragma unroll
                    for (int fn = 0; fn < 4; ++fn) {
                        int col = wn + fn * 16 + ln;
                        float vv = acc[fm][fn][r];
                        C[(size_t)row * 128 + col] = vv * inv;
                        Cb[(size_t)row * 128 + col] = f2b(vv);
                    }
                }
            }
    }
}

// ---------------------------------------------------------------------------
// Fused FFN: x2 = LN2( gelu(x1@w1^T+b1) @ w2^T + b2 + x1 ).  h stays in LDS.
// Block = 64 tokens, 8 chunks of 64 h-cols. grid 256.
// ---------------------------------------------------------------------------
__global__ __launch_bounds__(256) void ffn_fused(
    const unsigned short* __restrict__ x1b, const float* __restrict__ x1,
    const unsigned short* __restrict__ w1, const unsigned short* __restrict__ w2,
    const float* __restrict__ b1, const float* __restrict__ b2,
    const float* __restrict__ lng, const float* __restrict__ lnb,
    float* __restrict__ x2)
{
    __shared__ unsigned short Xs[64 * 136];
    __shared__ unsigned short W1s[64 * 136];
    __shared__ unsigned short Hs[64 * 72];
    __shared__ unsigned short W2s[128 * 72];
    __shared__ float red[2][64][2];
    const int tid = threadIdx.x, t0 = blockIdx.x * 64;
    const int wv = tid >> 6, lane = tid & 63, ln = lane & 15, q = lane >> 4;
    const int wm1 = (wv >> 1) * 32, wn1 = (wv & 1) * 32;   // h tile 64x64
    const int wm2 = (wv >> 1) * 32, wn2 = (wv & 1) * 64;   // x2 tile 64x128

    const uint4* X4 = (const uint4*)(x1b + (size_t)t0 * 128);
    #pragma unroll
    for (int t = 0; t < 4; ++t) {
        int idx = tid + t * 256;
        int r = idx >> 4, c = idx & 15;
        *(uint4*)&Xs[r * 136 + c * 8] = X4[r * 16 + c];
    }

    f32x4 acc2[2][4] = {};
    for (int ch = 0; ch < 8; ++ch) {
        const int hc0 = ch * 64;
        const uint4* W14 = (const uint4*)(w1 + (size_t)hc0 * 128);
        #pragma unroll
        for (int t = 0; t < 4; ++t) {
            int idx = tid + t * 256;
            int r = idx >> 4, c = idx & 15;
            *(uint4*)&W1s[r * 136 + c * 8] = W14[r * 16 + c];
        }
        #pragma unroll
        for (int t = 0; t < 4; ++t) {
            int idx = tid + t * 256;           // 128 rows x 8 uint4
            int r = idx >> 3, c = idx & 7;
            *(uint4*)&W2s[r * 72 + c * 8] = *(const uint4*)&w2[(size_t)r * 512 + hc0 + c * 8];
        }
        __syncthreads();
        // --- h = x1 @ w1chunk^T ---
        f32x4 acc1[2][2] = {};
        #pragma unroll
        for (int kf = 0; kf < 4; ++kf) {
            bf16x8 a[2], b[2];
            #pragma unroll
            for (int fm = 0; fm < 2; ++fm)
                a[fm] = *(const bf16x8*)&Xs[(wm1 + fm * 16 + ln) * 136 + kf * 32 + q * 8];
            #pragma unroll
            for (int fn = 0; fn < 2; ++fn)
                b[fn] = *(const bf16x8*)&W1s[(wn1 + fn * 16 + ln) * 136 + kf * 32 + q * 8];
            #pragma unroll
            for (int fm = 0; fm < 2; ++fm)
                #pragma unroll
                for (int fn = 0; fn < 2; ++fn)
                    acc1[fm][fn] = __builtin_amdgcn_mfma_f32_16x16x32_bf16(a[fm], b[fn], acc1[fm][fn], 0, 0, 0);
        }
        #pragma unroll
        for (int fm = 0; fm < 2; ++fm)
            #pragma unroll
            for (int fn = 0; fn < 2; ++fn)
                #pragma unroll
                for (int r = 0; r < 4; ++r) {
                    int rl = wm1 + fm * 16 + q * 4 + r;
                    int col = wn1 + fn * 16 + ln;
                    float hv = acc1[fm][fn][r] + b1[hc0 + col];
                    Hs[rl * 72 + col] = f2b(gelu_exact(hv));
                }
        __syncthreads();
        // --- x2 += hchunk @ w2chunk^T (K=64) ---
        #pragma unroll
        for (int kf = 0; kf < 2; ++kf) {
            bf16x8 a[2], b[4];
            #pragma unroll
            for (int fm = 0; fm < 2; ++fm)
                a[fm] = *(const bf16x8*)&Hs[(wm2 + fm * 16 + ln) * 72 + kf * 32 + q * 8];
            #pragma unroll
            for (int fn = 0; fn < 4; ++fn)
                b[fn] = *(const bf16x8*)&W2s[(wn2 + fn * 16 + ln) * 72 + kf * 32 + q * 8];
            #pragma unroll
            for (int fm = 0; fm < 2; ++fm)
                #pragma unroll
                for (int fn = 0; fn < 4; ++fn)
                    acc2[fm][fn] = __builtin_amdgcn_mfma_f32_16x16x32_bf16(a[fm], b[fn], acc2[fm][fn], 0, 0, 0);
        }
        __syncthreads();
    }
    // --- epilogue: +b2 +x1 residual, LN2, write fp32 ---
    #pragma unroll
    for (int fm = 0; fm < 2; ++fm)
        #pragma unroll
        for (int r = 0; r < 4; ++r) {
            int rl = wm2 + fm * 16 + q * 4 + r;
            int row = t0 + rl;
            float s1 = 0.0f, s2 = 0.0f;
            #pragma unroll
            for (int fn = 0; fn < 4; ++fn) {
                int col = wn2 + fn * 16 + ln;
                float vv = acc2[fm][fn][r] + b2[col] + x1[(size_t)row * 128 + col];
                acc2[fm][fn][r] = vv;
                s1 += vv; s2 += vv * vv;
            }
            #pragma unroll
            for (int off = 1; off < 16; off <<= 1) {
                s1 += __shfl_xor(s1, off, 64);
                s2 += __shfl_xor(s2, off, 64);
            }
            if (ln == 0) { red[0][rl][wv & 1] = s1; red[1][rl][wv & 1] = s2; }
        }
    __syncthreads();
    #pragma unroll
    for (int fm = 0; fm < 2; ++fm)
        #pragma unroll
        for (int r = 0; r < 4; ++r) {
            int rl = wm2 + fm * 16 + q * 4 + r;
            int row = t0 + rl;
            float mu = (red[0][rl][0] + red[0][rl][1]) * (1.0f / 128.0f);
            float var = (red[1][rl][0] + red[1][rl][1]) * (1.0f / 128.0f) - mu * mu;
            float rs = rsqrtf(var + 1e-5f);
            #pragma unroll
            for (int fn = 0; fn < 4; ++fn) {
                int col = wn2 + fn * 16 + ln;
                x2[(size_t)row * 128 + col] = (acc2[fm][fn][r] - mu) * rs * lng[col] + lnb[col];
            }
        }
}

// ---------------------------------------------------------------------------
__global__ __launch_bounds__(256) void convert3_kernel(
    const float* __restrict__ x, const float* __restrict__ sp, const float* __restrict__ tp,
    unsigned short* __restrict__ xb, unsigned short* __restrict__ spb, unsigned short* __restrict__ tpb)
{
    const int per = NTOK * 128 / 4;
    int i = blockIdx.x * 256 + threadIdx.x;
    int t = i / per, r = i % per;
    const float* s = (t == 0) ? x : (t == 1) ? sp : tp;
    unsigned short* d = (t == 0) ? xb : (t == 1) ? spb : tpb;
    float4 v = *(const float4*)&s[(size_t)r * 4];
    ushort4 o = {f2b(v.x), f2b(v.y), f2b(v.z), f2b(v.w)};
    *(ushort4*)&d[(size_t)r * 4] = o;
}

__global__ __launch_bounds__(256) void convertW_kernel(
    const float* __restrict__ w0, const float* __restrict__ w1,
    const float* __restrict__ w2, const float* __restrict__ w3,
    const float* __restrict__ w4, const float* __restrict__ w5,
    const float* __restrict__ w6, const float* __restrict__ w7,
    unsigned short* __restrict__ dst)
{
    int i = blockIdx.x * 256 + threadIdx.x;
    const float* s; int base;
    if      (i < 49152)  { s = w0; base = 0; }
    else if (i < 65536)  { s = w1; base = 49152; }
    else if (i < 131072) { s = w2; base = 65536; }
    else if (i < 196608) { s = w3; base = 131072; }
    else if (i < 212992) { s = w4; base = 196608; }
    else if (i < 229376) { s = w5; base = 212992; }
    else if (i < 278528) { s = w6; base = 229376; }
    else                 { s = w7; base = 278528; }
    dst[i] = f2b(s[i - base]);
}

// ---------------------------------------------------------------------------
// Windowed causal attention, bf16 qkv (NTOK,384), out bf16 (NTOK,128).
// ---------------------------------------------------------------------------
__global__ __launch_bounds__(64) void win_attn_kernel(
    const unsigned short* __restrict__ qkv, unsigned short* __restrict__ out)
{
    const int w = blockIdx.x, h = blockIdx.y, l = threadIdx.x;
    __shared__ float Ks[64][16];
    __shared__ float Vs[64][16];
    const unsigned short* base = qkv + (size_t)(w * 64 + l) * 384 + h * 16;
    #pragma unroll
    for (int c8 = 0; c8 < 16; c8 += 8) {
        uint4 kv = *(const uint4*)(base + 128 + c8);
        uint4 vv = *(const uint4*)(base + 256 + c8);
        const unsigned short* kp = (const unsigned short*)&kv;
        const unsigned short* vp = (const unsigned short*)&vv;
        #pragma unroll
        for (int c = 0; c < 8; ++c) { Ks[l][c8 + c] = b2f(kp[c]); Vs[l][c8 + c] = b2f(vp[c]); }
    }
    float qr[16];
    #pragma unroll
    for (int c8 = 0; c8 < 16; c8 += 8) {
        uint4 qv = *(const uint4*)(base + c8);
        const unsigned short* qp = (const unsigned short*)&qv;
        #pragma unroll
        for (int c = 0; c < 8; ++c) qr[c8 + c] = b2f(qp[c]);
    }
    __syncthreads();

    float m = -1e30f, ssum = 0.0f;
    float o[16] = {};
    for (int j = 0; j <= l; ++j) {
        float s = 0.0f;
        #pragma unroll
        for (int c = 0; c < 16; ++c) s = fmaf(qr[c], Ks[j][c], s);
        s *= 0.25f;
        float mnew = fmaxf(m, s);
        float corr = expf(m - mnew);
        float p = expf(s - mnew);
        ssum = ssum * corr + p;
        #pragma unroll
        for (int c = 0; c < 16; ++c) o[c] = o[c] * corr + p * Vs[j][c];
        m = mnew;
    }
    float inv = 1.0f / ssum;
    unsigned short* op = out + (size_t)(w * 64 + l) * 128 + h * 16;
    #pragma unroll
    for (int c = 0; c < 16; ++c) op[c] = f2b(o[c] * inv);
}

// ---------------------------------------------------------------------------
// Split-K A^T B per batch (fp32)
// ---------------------------------------------------------------------------
__global__ __launch_bounds__(256) void atb_split_kernel(
    const float* __restrict__ sn, const float* __restrict__ tn,
    float* __restrict__ part)
{
    const int b = blockIdx.z / ATB_SPLIT;
    const int chunk = blockIdx.z % ATB_SPLIT;
    const int d0 = blockIdx.x * 64, e0 = blockIdx.y * 64;
    __shared__ float Ss[32][68];
    __shared__ float Ts[32][68];
    const int tid = threadIdx.x;
    const int tx = tid % 16, ty = tid / 16;
    const float* sb = sn + (size_t)b * SS * 128;
    const float* tb = tn + (size_t)b * SS * 128;
    const int jbase = chunk * (SS / ATB_SPLIT);
    float acc[4][4] = {};
    for (int j0 = jbase; j0 < jbase + SS / ATB_SPLIT; j0 += 32) {
        #pragma unroll
        for (int it = 0; it < 2; ++it) {
            int idx = tid + it * 256;
            int r = idx / 16, c4 = (idx % 16) * 4;
            *(float4*)&Ss[r][c4] = *(const float4*)&sb[(size_t)(j0 + r) * 128 + d0 + c4];
            *(float4*)&Ts[r][c4] = *(const float4*)&tb[(size_t)(j0 + r) * 128 + e0 + c4];
        }
        __syncthreads();
        #pragma unroll
        for (int kk = 0; kk < 32; ++kk) {
            float4 af = *(const float4*)&Ss[kk][ty * 4];
            float4 wf = *(const float4*)&Ts[kk][tx * 4];
            float a[4] = {af.x, af.y, af.z, af.w};
            float w[4] = {wf.x, wf.y, wf.z, wf.w};
            #pragma unroll
            for (int i = 0; i < 4; ++i)
                #pragma unroll
                for (int j = 0; j < 4; ++j)
                    acc[i][j] = fmaf(a[i], w[j], acc[i][j]);
        }
        __syncthreads();
    }
    float* pp = part + (size_t)(b * ATB_SPLIT + chunk) * 16384;
    #pragma unroll
    for (int i = 0; i < 4; ++i) {
        float4 ov = {acc[i][0], acc[i][1], acc[i][2], acc[i][3]};
        *(float4*)&pp[(size_t)(d0 + ty * 4 + i) * 128 + e0 + tx * 4] = ov;
    }
}

__global__ __launch_bounds__(256) void atb_reduce_kernel(
    const float* __restrict__ part, float* __restrict__ Mb)
{
    int i = blockIdx.x * 256 + threadIdx.x;
    int b = i / 16384, pos = i % 16384;
    const float* pp = part + (size_t)b * ATB_SPLIT * 16384 + pos;
    float s = 0.0f;
    #pragma unroll
    for (int c = 0; c < ATB_SPLIT; ++c) s += pp[(size_t)c * 16384];
    Mb[i] = s;
}

// ---------------------------------------------------------------------------
__global__ __launch_bounds__(256) void sim_kernel(
    const float* __restrict__ sn, const float* __restrict__ tn,
    const float* __restrict__ Mb, float* __restrict__ sim)
{
    const int row0 = blockIdx.x * 16;
    const int b = row0 / SS;
    __shared__ float sn_s[16][128];
    __shared__ float tn_s[16][128];
    __shared__ float red[16][128];
    const int tid = threadIdx.x;
    for (int i4 = tid; i4 < 512; i4 += 256) {
        int r = i4 / 32, c4 = (i4 % 32) * 4;
        *(float4*)&sn_s[r][c4] = *(const float4*)&sn[(size_t)(row0 + r) * 128 + c4];
        *(float4*)&tn_s[r][c4] = *(const float4*)&tn[(size_t)(row0 + r) * 128 + c4];
    }
    __syncthreads();
    const int e = tid % 128, half = tid / 128;
    float acc[8] = {};
    const float* Mp = Mb + (size_t)b * 16384;
    for (int d = 0; d < 128; ++d) {
        float mv = Mp[(size_t)d * 128 + e];
        #pragma unroll
        for (int r = 0; r < 8; ++r) acc[r] = fmaf(sn_s[half * 8 + r][d], mv, acc[r]);
    }
    #pragma unroll
    for (int r = 0; r < 8; ++r) red[half * 8 + r][e] = acc[r] * tn_s[half * 8 + r][e];
    __syncthreads();
    if (tid < 16) {
        float s = 0.0f;
        for (int e2 = 0; e2 < 128; ++e2) s += red[tid][e2];
        sim[row0 + tid] = s * (1.0f / (float)SS);
    }
}

// ---------------------------------------------------------------------------
// Interaction attention (len=8 over batch, heads=8, hd=16), bf16 in/out.
// ---------------------------------------------------------------------------
__global__ __launch_bounds__(64) void inter_attn_kernel(
    const unsigned short* __restrict__ qkvi, unsigned short* __restrict__ AO)
{
    const int s = blockIdx.x, tid = threadIdx.x;
    __shared__ float Q[8][128];
    __shared__ float Km[8][128];
    __shared__ float Vm[8][128];
    __shared__ float P[8][8][8];
    for (int idx = tid; idx < 384; idx += 64) {    // 384 uint4 = 3*8*128 bf16
        int mat = idx / 128, rem = idx % 128;
        int i = rem / 16, c8 = (rem % 16) * 8;
        uint4 v = *(const uint4*)(qkvi + (size_t)(i * SS + s) * 384 + mat * 128 + c8);
        const unsigned short* vp = (const unsigned short*)&v;
        float* dst = (mat == 0) ? &Q[i][c8] : (mat == 1) ? &Km[i][c8] : &Vm[i][c8];
        #pragma unroll
        for (int c = 0; c < 8; ++c) dst[c] = b2f(vp[c]);
    }
    __syncthreads();
    for (int idx = tid; idx < 512; idx += 64) {
        int h = idx >> 6, i = (idx >> 3) & 7, j = idx & 7;
        float sum = 0.0f;
        #pragma unroll
        for (int c = 0; c < 16; ++c) sum = fmaf(Q[i][h * 16 + c], Km[j][h * 16 + c], sum);
        P[h][i][j] = sum * 0.25f;
    }
    __syncthreads();
    {
        int h = tid >> 3, i = tid & 7;
        float m = -1e30f;
        #pragma unroll
        for (int j = 0; j < 8; ++j) m = fmaxf(m, P[h][i][j]);
        float pj[8], ssum = 0.0f;
        #pragma unroll
        for (int j = 0; j < 8; ++j) { pj[j] = expf(P[h][i][j] - m); ssum += pj[j]; }
        float inv = 1.0f / ssum;
        #pragma unroll
        for (int j = 0; j < 8; ++j) P[h][i][j] = pj[j] * inv;
    }
    __syncthreads();
    for (int o = tid; o < 1024; o += 64) {
        int i = o >> 7, c = o & 127, h = c >> 4;
        float sum = 0.0f;
        #pragma unroll
        for (int j = 0; j < 8; ++j) sum = fmaf(P[h][i][j], Vm[j][c], sum);
        AO[(size_t)(i * SS + s) * 128 + c] = f2b(sum);
    }
}

// ---------------------------------------------------------------------------
extern "C" void kernel_launch(void* const* d_in, const int* in_sizes, int n_in,
                              void* d_out, int out_size, void* d_ws, size_t ws_size,
                              hipStream_t stream)
{
    const float* x        = (const float*)d_in[0];
    const float* spatial  = (const float*)d_in[1];
    const float* temporal = (const float*)d_in[2];
    const float* lw_in_b  = (const float*)d_in[4];
    const float* lw_out_b = (const float*)d_in[6];
    const float* spat_b   = (const float*)d_in[8];
    const float* temp_b   = (const float*)d_in[10];
    const float* int_in_b = (const float*)d_in[12];
    const float* int_out_b= (const float*)d_in[14];
    const float* ffn_b1   = (const float*)d_in[16];
    const float* ffn_b2   = (const float*)d_in[18];
    const float* ln1_g    = (const float*)d_in[19];
    const float* ln1_b    = (const float*)d_in[20];
    const float* ln2_g    = (const float*)d_in[21];
    const float* ln2_b    = (const float*)d_in[22];
    float* out = (float*)d_out;

    // ---- workspace layout (bytes) ----
    char* base = (char*)d_ws;
    unsigned short* qkvb = (unsigned short*)(base + 0);          // 12,582,912
    unsigned short* attnb= (unsigned short*)(base + 12582912);   //  4,194,304
    float*          x1   = (float*)(base + 16777216);            //  8,388,608 (alias: part)
    unsigned short* x1b  = (unsigned short*)(base + 25165824);   //  4,194,304
    float*          x2   = (float*)(base + 29360128);            //  8,388,608
    float*          sn   = (float*)(base + 37748736);            //  8,388,608
    float*          tn   = (float*)(base + 46137344);            //  8,388,608
    unsigned short* seb  = (unsigned short*)(base + 54525952);   //  4,194,304
    unsigned short* teb  = (unsigned short*)(base + 58720256);   //  4,194,304
    float*          Mb   = (float*)(base + 62914560);            //    524,288
    float*          simb = (float*)(base + 63438848);            //     65,536
    unsigned short* xb   = (unsigned short*)(base + 63504384);   //  4,194,304
    unsigned short* spb  = (unsigned short*)(base + 67698688);   //  4,194,304
    unsigned short* tpb  = (unsigned short*)(base + 71892992);   //  4,194,304
    unsigned short* Wb   = (unsigned short*)(base + 76087296);   //  1,179,648
    float*          part = x1;   // alias: x1 dead after ffn_fused, atb runs later

    unsigned short* Wb_lwin  = Wb + 0;
    unsigned short* Wb_lwout = Wb + 49152;
    unsigned short* Wb_ffn1  = Wb + 65536;
    unsigned short* Wb_ffn2  = Wb + 131072;
    unsigned short* Wb_spat  = Wb + 196608;
    unsigned short* Wb_temp  = Wb + 212992;
    unsigned short* Wb_intin = Wb + 229376;
    unsigned short* Wb_intout= Wb + 278528;

    // --- 0. conversions ---
    convert3_kernel<<<6144, 256, 0, stream>>>(x, spatial, temporal, xb, spb, tpb);
    convertW_kernel<<<1152, 256, 0, stream>>>(
        (const float*)d_in[3], (const float*)d_in[5], (const float*)d_in[15],
        (const float*)d_in[17], (const float*)d_in[7], (const float*)d_in[9],
        (const float*)d_in[11], (const float*)d_in[13], Wb);

    // --- 1. window QKV -> qkvb bf16 ---
    gemm_k128<<<dim3(256, 3), 256, 0, stream>>>(
        xb, Wb_lwin, lw_in_b, nullptr, nullptr, nullptr, nullptr,
        nullptr, qkvb, 384, 0);
    // --- 2. windowed causal attention -> attnb bf16 ---
    win_attn_kernel<<<dim3(256, 8), 64, 0, stream>>>(qkvb, attnb);
    // --- 3. out-proj + residual(x) + LN1 -> x1 fp32, x1b bf16 ---
    gemm_k128<<<dim3(256, 1), 256, 0, stream>>>(
        attnb, Wb_lwout, lw_out_b, x, nullptr, ln1_g, ln1_b,
        x1, x1b, 128, 2);
    // --- 4. fused FFN + LN2 -> x2 fp32 ---
    ffn_fused<<<256, 256, 0, stream>>>(
        x1b, x1, Wb_ffn1, Wb_ffn2, ffn_b1, ffn_b2, ln2_g, ln2_b, x2);
    // --- 5/6. se, te projections + cos-norm -> sn/tn fp32 (normed), seb/teb bf16 (raw) ---
    gemm_k128<<<dim3(256, 1), 256, 0, stream>>>(
        spb, Wb_spat, spat_b, nullptr, nullptr, nullptr, nullptr,
        sn, seb, 128, 3);
    gemm_k128<<<dim3(256, 1), 256, 0, stream>>>(
        tpb, Wb_temp, temp_b, nullptr, nullptr, nullptr, nullptr,
        tn, teb, 128, 3);
    // --- 7. M_b = sn^T tn per batch ---
    atb_split_kernel<<<dim3(2, 2, 8 * ATB_SPLIT), 256, 0, stream>>>(sn, tn, part);
    atb_reduce_kernel<<<512, 256, 0, stream>>>(part, Mb);
    // --- 8. sim ---
    sim_kernel<<<NTOK / 16, 256, 0, stream>>>(sn, tn, Mb, simb);
    // --- 9. interaction QKV: q from seb, k/v from teb -> qkvb ---
    gemm_k128<<<dim3(256, 1), 256, 0, stream>>>(
        seb, Wb_intin, int_in_b, nullptr, nullptr, nullptr, nullptr,
        nullptr, qkvb, 384, 0);
    gemm_k128<<<dim3(256, 2), 256, 0, stream>>>(
        teb, Wb_intin + 16384, int_in_b + 128, nullptr, nullptr, nullptr, nullptr,
        nullptr, qkvb + 128, 384, 0);
    // --- 10. interaction attention -> attnb ---
    inter_attn_kernel<<<SS, 64, 0, stream>>>(qkvb, attnb);
    // --- 11. final: out = x2 + sim * (attnb @ Wout^T + bout) ---
    gemm_k128<<<dim3(256, 1), 256, 0, stream>>>(
        attnb, Wb_intout, int_out_b, x2, simb, nullptr, nullptr,
        out, nullptr, 128, 0);
}

// Round 5
// 253.573 us; speedup vs baseline: 1.4744x; 1.0771x over previous
//
#include <hip/hip_runtime.h>
#include <math.h>

#define BB 8
#define SS 2048
#define NTOK (BB * SS)   // 16384
#define ATB_SPLIT 16

using bf16x8 = __attribute__((ext_vector_type(8))) short;
using f32x4  = __attribute__((ext_vector_type(4))) float;

__device__ __forceinline__ float gelu_exact(float v) {
    return 0.5f * v * (1.0f + erff(v * 0.70710678118654752f));
}
__device__ __forceinline__ unsigned short f2b(float f) {
    unsigned int u = __float_as_uint(f);
    u += 0x7FFFu + ((u >> 16) & 1u);
    return (unsigned short)(u >> 16);
}
__device__ __forceinline__ float b2f(unsigned short u) {
    return __uint_as_float((unsigned int)u << 16);
}

// ---------------------------------------------------------------------------
// Single-stage K=128 bf16 MFMA GEMM. Block: 64 rows x 128 cols.
// A sources: Af (fp32, converted on the fly) OR A bf16; if A2!=null and
// blockIdx.y>0, A2 is used (interaction QKV: q from se, k/v from te).
// mode 0: v=(acc+bias)*scale(+res) -> C fp32 / Cb bf16
// mode 2: v=acc+bias+res -> LayerNorm(g,b) -> C fp32 + Cb bf16 (ldc=128)
// ---------------------------------------------------------------------------
__global__ __launch_bounds__(256) void gemm_k128(
    const unsigned short* __restrict__ A, const float* __restrict__ Af,
    const unsigned short* __restrict__ A2,
    const unsigned short* __restrict__ W,
    const float* __restrict__ bias, const float* __restrict__ res,
    const float* __restrict__ scale,
    const float* __restrict__ lng, const float* __restrict__ lnb,
    float* __restrict__ C, unsigned short* __restrict__ Cb,
    int ldc, int mode)
{
    __shared__ unsigned short As[64 * 136];
    __shared__ unsigned short Ws[128 * 136];
    __shared__ float red[2][64][2];
    const int tid = threadIdx.x;
    const int m0 = blockIdx.x * 64, n0 = blockIdx.y * 128;

    if (Af != nullptr) {
        const float4* A4 = (const float4*)(Af + (size_t)m0 * 128);
        #pragma unroll
        for (int t = 0; t < 4; ++t) {
            int idx = tid + t * 256;
            int r = idx >> 4, c = idx & 15;
            float4 f0 = A4[r * 32 + c * 2];
            float4 f1 = A4[r * 32 + c * 2 + 1];
            ushort4 lo = {f2b(f0.x), f2b(f0.y), f2b(f0.z), f2b(f0.w)};
            ushort4 hi = {f2b(f1.x), f2b(f1.y), f2b(f1.z), f2b(f1.w)};
            *(ushort4*)&As[r * 136 + c * 8] = lo;
            *(ushort4*)&As[r * 136 + c * 8 + 4] = hi;
        }
    } else {
        const unsigned short* Ause = (A2 != nullptr && blockIdx.y > 0) ? A2 : A;
        const uint4* A4 = (const uint4*)(Ause + (size_t)m0 * 128);
        #pragma unroll
        for (int t = 0; t < 4; ++t) {
            int idx = tid + t * 256;
            int r = idx >> 4, c = idx & 15;
            *(uint4*)&As[r * 136 + c * 8] = A4[r * 16 + c];
        }
    }
    const uint4* W4 = (const uint4*)(W + (size_t)n0 * 128);
    #pragma unroll
    for (int t = 0; t < 8; ++t) {
        int idx = tid + t * 256;
        int r = idx >> 4, c = idx & 15;
        *(uint4*)&Ws[r * 136 + c * 8] = W4[r * 16 + c];
    }
    __syncthreads();

    const int wv = tid >> 6, lane = tid & 63, ln = lane & 15, q = lane >> 4;
    const int wm = (wv >> 1) * 32, wn = (wv & 1) * 64;
    f32x4 acc[2][4] = {};
    #pragma unroll
    for (int kf = 0; kf < 4; ++kf) {
        bf16x8 a[2], b[4];
        #pragma unroll
        for (int fm = 0; fm < 2; ++fm)
            a[fm] = *(const bf16x8*)&As[(wm + fm * 16 + ln) * 136 + kf * 32 + q * 8];
        #pragma unroll
        for (int fn = 0; fn < 4; ++fn)
            b[fn] = *(const bf16x8*)&Ws[(wn + fn * 16 + ln) * 136 + kf * 32 + q * 8];
        #pragma unroll
        for (int fm = 0; fm < 2; ++fm)
            #pragma unroll
            for (int fn = 0; fn < 4; ++fn)
                acc[fm][fn] = __builtin_amdgcn_mfma_f32_16x16x32_bf16(a[fm], b[fn], acc[fm][fn], 0, 0, 0);
    }

    float bcol[4];
    #pragma unroll
    for (int fn = 0; fn < 4; ++fn) bcol[fn] = bias[n0 + wn + fn * 16 + ln];

    if (mode == 0) {
        #pragma unroll
        for (int fm = 0; fm < 2; ++fm)
            #pragma unroll
            for (int r = 0; r < 4; ++r) {
                int row = m0 + wm + fm * 16 + q * 4 + r;
                float sc = (scale != nullptr) ? scale[row] : 1.0f;
                #pragma unroll
                for (int fn = 0; fn < 4; ++fn) {
                    int col = n0 + wn + fn * 16 + ln;
                    float vv = (acc[fm][fn][r] + bcol[fn]) * sc;
                    size_t off = (size_t)row * ldc + col;
                    if (res != nullptr) vv += res[off];
                    if (C != nullptr) C[off] = vv;
                    if (Cb != nullptr) Cb[off] = f2b(vv);
                }
            }
    } else {
        #pragma unroll
        for (int fm = 0; fm < 2; ++fm)
            #pragma unroll
            for (int r = 0; r < 4; ++r) {
                int rl = wm + fm * 16 + q * 4 + r;
                int row = m0 + rl;
                float s1 = 0.0f, s2 = 0.0f;
                #pragma unroll
                for (int fn = 0; fn < 4; ++fn) {
                    int col = wn + fn * 16 + ln;
                    float vv = acc[fm][fn][r] + bcol[fn] + res[(size_t)row * 128 + col];
                    acc[fm][fn][r] = vv;
                    s1 += vv; s2 += vv * vv;
                }
                #pragma unroll
                for (int off = 1; off < 16; off <<= 1) {
                    s1 += __shfl_xor(s1, off, 64);
                    s2 += __shfl_xor(s2, off, 64);
                }
                if (ln == 0) { red[0][rl][wv & 1] = s1; red[1][rl][wv & 1] = s2; }
            }
        __syncthreads();
        #pragma unroll
        for (int fm = 0; fm < 2; ++fm)
            #pragma unroll
            for (int r = 0; r < 4; ++r) {
                int rl = wm + fm * 16 + q * 4 + r;
                int row = m0 + rl;
                float mu = (red[0][rl][0] + red[0][rl][1]) * (1.0f / 128.0f);
                float var = (red[1][rl][0] + red[1][rl][1]) * (1.0f / 128.0f) - mu * mu;
                float rs = rsqrtf(var + 1e-5f);
                #pragma unroll
                for (int fn = 0; fn < 4; ++fn) {
                    int col = wn + fn * 16 + ln;
                    float o = (acc[fm][fn][r] - mu) * rs * lng[col] + lnb[col];
                    C[(size_t)row * 128 + col] = o;
                    Cb[(size_t)row * 128 + col] = f2b(o);
                }
            }
    }
}

// ---------------------------------------------------------------------------
// se/te projection + cosine norm. grid (256,2): y=0 spatial, y=1 temporal.
// A fp32 (converted on the fly). Outputs: nrm fp32 (normed), nb bf16 (normed,
// y=0 only), raw bf16.
// ---------------------------------------------------------------------------
__global__ __launch_bounds__(256) void stproj_kernel(
    const float* __restrict__ sp, const float* __restrict__ tp,
    const unsigned short* __restrict__ Wsp, const unsigned short* __restrict__ Wtp,
    const float* __restrict__ bsp, const float* __restrict__ btp,
    float* __restrict__ sn, float* __restrict__ tn,
    unsigned short* __restrict__ snb,
    unsigned short* __restrict__ seb, unsigned short* __restrict__ teb)
{
    __shared__ unsigned short As[64 * 136];
    __shared__ unsigned short Ws[128 * 136];
    __shared__ float red[64][2];
    const int tid = threadIdx.x;
    const int m0 = blockIdx.x * 64;
    const int y = blockIdx.y;
    const float* Af = y ? tp : sp;
    const unsigned short* W = y ? Wtp : Wsp;
    const float* bias = y ? btp : bsp;
    float* nrm = y ? tn : sn;
    unsigned short* nb = y ? nullptr : snb;
    unsigned short* raw = y ? teb : seb;

    const float4* A4 = (const float4*)(Af + (size_t)m0 * 128);
    #pragma unroll
    for (int t = 0; t < 4; ++t) {
        int idx = tid + t * 256;
        int r = idx >> 4, c = idx & 15;
        float4 f0 = A4[r * 32 + c * 2];
        float4 f1 = A4[r * 32 + c * 2 + 1];
        ushort4 lo = {f2b(f0.x), f2b(f0.y), f2b(f0.z), f2b(f0.w)};
        ushort4 hi = {f2b(f1.x), f2b(f1.y), f2b(f1.z), f2b(f1.w)};
        *(ushort4*)&As[r * 136 + c * 8] = lo;
        *(ushort4*)&As[r * 136 + c * 8 + 4] = hi;
    }
    const uint4* W4 = (const uint4*)W;
    #pragma unroll
    for (int t = 0; t < 8; ++t) {
        int idx = tid + t * 256;
        int r = idx >> 4, c = idx & 15;
        *(uint4*)&Ws[r * 136 + c * 8] = W4[r * 16 + c];
    }
    __syncthreads();

    const int wv = tid >> 6, lane = tid & 63, ln = lane & 15, q = lane >> 4;
    const int wm = (wv >> 1) * 32, wn = (wv & 1) * 64;
    f32x4 acc[2][4] = {};
    #pragma unroll
    for (int kf = 0; kf < 4; ++kf) {
        bf16x8 a[2], b[4];
        #pragma unroll
        for (int fm = 0; fm < 2; ++fm)
            a[fm] = *(const bf16x8*)&As[(wm + fm * 16 + ln) * 136 + kf * 32 + q * 8];
        #pragma unroll
        for (int fn = 0; fn < 4; ++fn)
            b[fn] = *(const bf16x8*)&Ws[(wn + fn * 16 + ln) * 136 + kf * 32 + q * 8];
        #pragma unroll
        for (int fm = 0; fm < 2; ++fm)
            #pragma unroll
            for (int fn = 0; fn < 4; ++fn)
                acc[fm][fn] = __builtin_amdgcn_mfma_f32_16x16x32_bf16(a[fm], b[fn], acc[fm][fn], 0, 0, 0);
    }
    float bcol[4];
    #pragma unroll
    for (int fn = 0; fn < 4; ++fn) bcol[fn] = bias[wn + fn * 16 + ln];

    #pragma unroll
    for (int fm = 0; fm < 2; ++fm)
        #pragma unroll
        for (int r = 0; r < 4; ++r) {
            int rl = wm + fm * 16 + q * 4 + r;
            float s2 = 0.0f;
            #pragma unroll
            for (int fn = 0; fn < 4; ++fn) {
                float vv = acc[fm][fn][r] + bcol[fn];
                acc[fm][fn][r] = vv;
                s2 += vv * vv;
            }
            #pragma unroll
            for (int off = 1; off < 16; off <<= 1) s2 += __shfl_xor(s2, off, 64);
            if (ln == 0) red[rl][wv & 1] = s2;
        }
    __syncthreads();
    #pragma unroll
    for (int fm = 0; fm < 2; ++fm)
        #pragma unroll
        for (int r = 0; r < 4; ++r) {
            int rl = wm + fm * 16 + q * 4 + r;
            int row = m0 + rl;
            float inv = 1.0f / fmaxf(sqrtf(red[rl][0] + red[rl][1]), 1e-8f);
            #pragma unroll
            for (int fn = 0; fn < 4; ++fn) {
                int col = wn + fn * 16 + ln;
                float vv = acc[fm][fn][r];
                float nv = vv * inv;
                nrm[(size_t)row * 128 + col] = nv;
                if (nb != nullptr) nb[(size_t)row * 128 + col] = f2b(nv);
                raw[(size_t)row * 128 + col] = f2b(vv);
            }
        }
}

// ---------------------------------------------------------------------------
// sim via MFMA: P = snb @ Mt_b^T-ish (W[e][d] = M[d][e]); sim = <P,tn>/S.
// grid 256, block covers 64 rows x 128 cols.
// ---------------------------------------------------------------------------
__global__ __launch_bounds__(256) void simgemm_kernel(
    const unsigned short* __restrict__ snb, const float* __restrict__ tn,
    const unsigned short* __restrict__ Mtb, float* __restrict__ sim)
{
    __shared__ unsigned short As[64 * 136];
    __shared__ unsigned short Ws[128 * 136];
    __shared__ float red[64][2];
    const int tid = threadIdx.x;
    const int m0 = blockIdx.x * 64;
    const int b = m0 >> 11;

    const uint4* A4 = (const uint4*)(snb + (size_t)m0 * 128);
    #pragma unroll
    for (int t = 0; t < 4; ++t) {
        int idx = tid + t * 256;
        int r = idx >> 4, c = idx & 15;
        *(uint4*)&As[r * 136 + c * 8] = A4[r * 16 + c];
    }
    const uint4* W4 = (const uint4*)(Mtb + (size_t)b * 16384);
    #pragma unroll
    for (int t = 0; t < 8; ++t) {
        int idx = tid + t * 256;
        int r = idx >> 4, c = idx & 15;
        *(uint4*)&Ws[r * 136 + c * 8] = W4[r * 16 + c];
    }
    __syncthreads();

    const int wv = tid >> 6, lane = tid & 63, ln = lane & 15, q = lane >> 4;
    const int wm = (wv >> 1) * 32, wn = (wv & 1) * 64;
    f32x4 acc[2][4] = {};
    #pragma unroll
    for (int kf = 0; kf < 4; ++kf) {
        bf16x8 a[2], b2[4];
        #pragma unroll
        for (int fm = 0; fm < 2; ++fm)
            a[fm] = *(const bf16x8*)&As[(wm + fm * 16 + ln) * 136 + kf * 32 + q * 8];
        #pragma unroll
        for (int fn = 0; fn < 4; ++fn)
            b2[fn] = *(const bf16x8*)&Ws[(wn + fn * 16 + ln) * 136 + kf * 32 + q * 8];
        #pragma unroll
        for (int fm = 0; fm < 2; ++fm)
            #pragma unroll
            for (int fn = 0; fn < 4; ++fn)
                acc[fm][fn] = __builtin_amdgcn_mfma_f32_16x16x32_bf16(a[fm], b2[fn], acc[fm][fn], 0, 0, 0);
    }
    #pragma unroll
    for (int fm = 0; fm < 2; ++fm)
        #pragma unroll
        for (int r = 0; r < 4; ++r) {
            int rl = wm + fm * 16 + q * 4 + r;
            int row = m0 + rl;
            float s = 0.0f;
            #pragma unroll
            for (int fn = 0; fn < 4; ++fn) {
                int col = wn + fn * 16 + ln;
                s += acc[fm][fn][r] * tn[(size_t)row * 128 + col];
            }
            #pragma unroll
            for (int off = 1; off < 16; off <<= 1) s += __shfl_xor(s, off, 64);
            if (ln == 0) red[rl][wv & 1] = s;
        }
    __syncthreads();
    if (tid < 64) {
        sim[m0 + tid] = (red[tid][0] + red[tid][1]) * (1.0f / (float)SS);
    }
}

// ---------------------------------------------------------------------------
// Fused FFN: x2 = LN2( gelu(x1@w1^T+b1) @ w2^T + b2 + x1 ). 32-token blocks.
// grid 512.
// ---------------------------------------------------------------------------
__global__ __launch_bounds__(256) void ffn_fused(
    const unsigned short* __restrict__ x1b, const float* __restrict__ x1,
    const unsigned short* __restrict__ w1, const unsigned short* __restrict__ w2,
    const float* __restrict__ b1, const float* __restrict__ b2,
    const float* __restrict__ lng, const float* __restrict__ lnb,
    float* __restrict__ x2)
{
    __shared__ unsigned short Xs[32 * 136];
    __shared__ unsigned short W1s[64 * 136];
    __shared__ unsigned short Hs[32 * 72];
    __shared__ unsigned short W2s[128 * 72];
    __shared__ float red[2][32][2];
    const int tid = threadIdx.x, t0 = blockIdx.x * 32;
    const int wv = tid >> 6, lane = tid & 63, ln = lane & 15, q = lane >> 4;
    const int wm1 = (wv >> 1) * 16, wn1 = (wv & 1) * 32;
    const int wm2 = (wv >> 1) * 16, wn2 = (wv & 1) * 64;

    const uint4* X4 = (const uint4*)(x1b + (size_t)t0 * 128);
    #pragma unroll
    for (int t = 0; t < 2; ++t) {
        int idx = tid + t * 256;
        int r = idx >> 4, c = idx & 15;
        *(uint4*)&Xs[r * 136 + c * 8] = X4[r * 16 + c];
    }

    f32x4 acc2[4] = {};
    for (int ch = 0; ch < 8; ++ch) {
        const int hc0 = ch * 64;
        const uint4* W14 = (const uint4*)(w1 + (size_t)hc0 * 128);
        #pragma unroll
        for (int t = 0; t < 4; ++t) {
            int idx = tid + t * 256;
            int r = idx >> 4, c = idx & 15;
            *(uint4*)&W1s[r * 136 + c * 8] = W14[r * 16 + c];
        }
        #pragma unroll
        for (int t = 0; t < 4; ++t) {
            int idx = tid + t * 256;
            int r = idx >> 3, c = idx & 7;
            *(uint4*)&W2s[r * 72 + c * 8] = *(const uint4*)&w2[(size_t)r * 512 + hc0 + c * 8];
        }
        __syncthreads();
        f32x4 acc1[2] = {};
        #pragma unroll
        for (int kf = 0; kf < 4; ++kf) {
            bf16x8 a = *(const bf16x8*)&Xs[(wm1 + ln) * 136 + kf * 32 + q * 8];
            #pragma unroll
            for (int fn = 0; fn < 2; ++fn) {
                bf16x8 bb = *(const bf16x8*)&W1s[(wn1 + fn * 16 + ln) * 136 + kf * 32 + q * 8];
                acc1[fn] = __builtin_amdgcn_mfma_f32_16x16x32_bf16(a, bb, acc1[fn], 0, 0, 0);
            }
        }
        #pragma unroll
        for (int fn = 0; fn < 2; ++fn)
            #pragma unroll
            for (int r = 0; r < 4; ++r) {
                int rl = wm1 + q * 4 + r;
                int col = wn1 + fn * 16 + ln;
                Hs[rl * 72 + col] = f2b(gelu_exact(acc1[fn][r] + b1[hc0 + col]));
            }
        __syncthreads();
        #pragma unroll
        for (int kf = 0; kf < 2; ++kf) {
            bf16x8 a = *(const bf16x8*)&Hs[(wm2 + ln) * 72 + kf * 32 + q * 8];
            #pragma unroll
            for (int fn = 0; fn < 4; ++fn) {
                bf16x8 bb = *(const bf16x8*)&W2s[(wn2 + fn * 16 + ln) * 72 + kf * 32 + q * 8];
                acc2[fn] = __builtin_amdgcn_mfma_f32_16x16x32_bf16(a, bb, acc2[fn], 0, 0, 0);
            }
        }
        __syncthreads();
    }
    #pragma unroll
    for (int r = 0; r < 4; ++r) {
        int rl = wm2 + q * 4 + r;
        int row = t0 + rl;
        float s1 = 0.0f, s2 = 0.0f;
        #pragma unroll
        for (int fn = 0; fn < 4; ++fn) {
            int col = wn2 + fn * 16 + ln;
            float vv = acc2[fn][r] + b2[col] + x1[(size_t)row * 128 + col];
            acc2[fn][r] = vv;
            s1 += vv; s2 += vv * vv;
        }
        #pragma unroll
        for (int off = 1; off < 16; off <<= 1) {
            s1 += __shfl_xor(s1, off, 64);
            s2 += __shfl_xor(s2, off, 64);
        }
        if (ln == 0) { red[0][rl][wv & 1] = s1; red[1][rl][wv & 1] = s2; }
    }
    __syncthreads();
    #pragma unroll
    for (int r = 0; r < 4; ++r) {
        int rl = wm2 + q * 4 + r;
        int row = t0 + rl;
        float mu = (red[0][rl][0] + red[0][rl][1]) * (1.0f / 128.0f);
        float var = (red[1][rl][0] + red[1][rl][1]) * (1.0f / 128.0f) - mu * mu;
        float rs = rsqrtf(var + 1e-5f);
        #pragma unroll
        for (int fn = 0; fn < 4; ++fn) {
            int col = wn2 + fn * 16 + ln;
            x2[(size_t)row * 128 + col] = (acc2[fn][r] - mu) * rs * lng[col] + lnb[col];
        }
    }
}

// ---------------------------------------------------------------------------
__global__ __launch_bounds__(256) void convertW_kernel(
    const float* __restrict__ w0, const float* __restrict__ w1,
    const float* __restrict__ w2, const float* __restrict__ w3,
    const float* __restrict__ w4, const float* __restrict__ w5,
    const float* __restrict__ w6, const float* __restrict__ w7,
    unsigned short* __restrict__ dst)
{
    int i = blockIdx.x * 256 + threadIdx.x;
    const float* s; int base;
    if      (i < 49152)  { s = w0; base = 0; }
    else if (i < 65536)  { s = w1; base = 49152; }
    else if (i < 131072) { s = w2; base = 65536; }
    else if (i < 196608) { s = w3; base = 131072; }
    else if (i < 212992) { s = w4; base = 196608; }
    else if (i < 229376) { s = w5; base = 212992; }
    else if (i < 278528) { s = w6; base = 229376; }
    else                 { s = w7; base = 278528; }
    dst[i] = f2b(s[i - base]);
}

// ---------------------------------------------------------------------------
// Windowed causal attention, bf16 qkv (NTOK,384), out bf16 (NTOK,128).
// ---------------------------------------------------------------------------
__global__ __launch_bounds__(64) void win_attn_kernel(
    const unsigned short* __restrict__ qkv, unsigned short* __restrict__ out)
{
    const int w = blockIdx.x, h = blockIdx.y, l = threadIdx.x;
    __shared__ float Ks[64][16];
    __shared__ float Vs[64][16];
    const unsigned short* base = qkv + (size_t)(w * 64 + l) * 384 + h * 16;
    #pragma unroll
    for (int c8 = 0; c8 < 16; c8 += 8) {
        uint4 kv = *(const uint4*)(base + 128 + c8);
        uint4 vv = *(const uint4*)(base + 256 + c8);
        const unsigned short* kp = (const unsigned short*)&kv;
        const unsigned short* vp = (const unsigned short*)&vv;
        #pragma unroll
        for (int c = 0; c < 8; ++c) { Ks[l][c8 + c] = b2f(kp[c]); Vs[l][c8 + c] = b2f(vp[c]); }
    }
    float qr[16];
    #pragma unroll
    for (int c8 = 0; c8 < 16; c8 += 8) {
        uint4 qv = *(const uint4*)(base + c8);
        const unsigned short* qp = (const unsigned short*)&qv;
        #pragma unroll
        for (int c = 0; c < 8; ++c) qr[c8 + c] = b2f(qp[c]);
    }
    __syncthreads();

    float m = -1e30f, ssum = 0.0f;
    float o[16] = {};
    for (int j = 0; j <= l; ++j) {
        float s = 0.0f;
        #pragma unroll
        for (int c = 0; c < 16; ++c) s = fmaf(qr[c], Ks[j][c], s);
        s *= 0.25f;
        float mnew = fmaxf(m, s);
        float corr = expf(m - mnew);
        float p = expf(s - mnew);
        ssum = ssum * corr + p;
        #pragma unroll
        for (int c = 0; c < 16; ++c) o[c] = o[c] * corr + p * Vs[j][c];
        m = mnew;
    }
    float inv = 1.0f / ssum;
    unsigned short* op = out + (size_t)(w * 64 + l) * 128 + h * 16;
    #pragma unroll
    for (int c = 0; c < 16; ++c) op[c] = f2b(o[c] * inv);
}

// ---------------------------------------------------------------------------
// Split-K A^T B per batch (fp32)
// ---------------------------------------------------------------------------
__global__ __launch_bounds__(256) void atb_split_kernel(
    const float* __restrict__ sn, const float* __restrict__ tn,
    float* __restrict__ part)
{
    const int b = blockIdx.z / ATB_SPLIT;
    const int chunk = blockIdx.z % ATB_SPLIT;
    const int d0 = blockIdx.x * 64, e0 = blockIdx.y * 64;
    __shared__ float Ss[32][68];
    __shared__ float Ts[32][68];
    const int tid = threadIdx.x;
    const int tx = tid % 16, ty = tid / 16;
    const float* sb = sn + (size_t)b * SS * 128;
    const float* tb = tn + (size_t)b * SS * 128;
    const int jbase = chunk * (SS / ATB_SPLIT);
    float acc[4][4] = {};
    for (int j0 = jbase; j0 < jbase + SS / ATB_SPLIT; j0 += 32) {
        #pragma unroll
        for (int it = 0; it < 2; ++it) {
            int idx = tid + it * 256;
            int r = idx / 16, c4 = (idx % 16) * 4;
            *(float4*)&Ss[r][c4] = *(const float4*)&sb[(size_t)(j0 + r) * 128 + d0 + c4];
            *(float4*)&Ts[r][c4] = *(const float4*)&tb[(size_t)(j0 + r) * 128 + e0 + c4];
        }
        __syncthreads();
        #pragma unroll
        for (int kk = 0; kk < 32; ++kk) {
            float4 af = *(const float4*)&Ss[kk][ty * 4];
            float4 wf = *(const float4*)&Ts[kk][tx * 4];
            float a[4] = {af.x, af.y, af.z, af.w};
            float w[4] = {wf.x, wf.y, wf.z, wf.w};
            #pragma unroll
            for (int i = 0; i < 4; ++i)
                #pragma unroll
                for (int j = 0; j < 4; ++j)
                    acc[i][j] = fmaf(a[i], w[j], acc[i][j]);
        }
        __syncthreads();
    }
    float* pp = part + (size_t)(b * ATB_SPLIT + chunk) * 16384;
    #pragma unroll
    for (int i = 0; i < 4; ++i) {
        float4 ov = {acc[i][0], acc[i][1], acc[i][2], acc[i][3]};
        *(float4*)&pp[(size_t)(d0 + ty * 4 + i) * 128 + e0 + tx * 4] = ov;
    }
}

// Mtb[b][e*128+d] = bf16( sum_chunk part[(b*16+c)*16384 + d*128 + e] )
__global__ __launch_bounds__(256) void atb_reduce_kernel(
    const float* __restrict__ part, unsigned short* __restrict__ Mtb)
{
    int i = blockIdx.x * 256 + threadIdx.x;   // 0..131071
    int b = i >> 14, rem = i & 16383;
    int e = rem >> 7, d = rem & 127;
    const float* pp = part + (size_t)b * ATB_SPLIT * 16384 + (size_t)d * 128 + e;
    float s = 0.0f;
    #pragma unroll
    for (int c = 0; c < ATB_SPLIT; ++c) s += pp[(size_t)c * 16384];
    Mtb[i] = f2b(s);
}

// ---------------------------------------------------------------------------
// Interaction attention (len=8 over batch, heads=8, hd=16), bf16 in/out.
// ---------------------------------------------------------------------------
__global__ __launch_bounds__(64) void inter_attn_kernel(
    const unsigned short* __restrict__ qkvi, unsigned short* __restrict__ AO)
{
    const int s = blockIdx.x, tid = threadIdx.x;
    __shared__ float Q[8][128];
    __shared__ float Km[8][128];
    __shared__ float Vm[8][128];
    __shared__ float P[8][8][8];
    for (int idx = tid; idx < 384; idx += 64) {
        int mat = idx / 128, rem = idx % 128;
        int i = rem / 16, c8 = (rem % 16) * 8;
        uint4 v = *(const uint4*)(qkvi + (size_t)(i * SS + s) * 384 + mat * 128 + c8);
        const unsigned short* vp = (const unsigned short*)&v;
        float* dst = (mat == 0) ? &Q[i][c8] : (mat == 1) ? &Km[i][c8] : &Vm[i][c8];
        #pragma unroll
        for (int c = 0; c < 8; ++c) dst[c] = b2f(vp[c]);
    }
    __syncthreads();
    for (int idx = tid; idx < 512; idx += 64) {
        int h = idx >> 6, i = (idx >> 3) & 7, j = idx & 7;
        float sum = 0.0f;
        #pragma unroll
        for (int c = 0; c < 16; ++c) sum = fmaf(Q[i][h * 16 + c], Km[j][h * 16 + c], sum);
        P[h][i][j] = sum * 0.25f;
    }
    __syncthreads();
    {
        int h = tid >> 3, i = tid & 7;
        float m = -1e30f;
        #pragma unroll
        for (int j = 0; j < 8; ++j) m = fmaxf(m, P[h][i][j]);
        float pj[8], ssum = 0.0f;
        #pragma unroll
        for (int j = 0; j < 8; ++j) { pj[j] = expf(P[h][i][j] - m); ssum += pj[j]; }
        float inv = 1.0f / ssum;
        #pragma unroll
        for (int j = 0; j < 8; ++j) P[h][i][j] = pj[j] * inv;
    }
    __syncthreads();
    for (int o = tid; o < 1024; o += 64) {
        int i = o >> 7, c = o & 127, h = c >> 4;
        float sum = 0.0f;
        #pragma unroll
        for (int j = 0; j < 8; ++j) sum = fmaf(P[h][i][j], Vm[j][c], sum);
        AO[(size_t)(i * SS + s) * 128 + c] = f2b(sum);
    }
}

// ---------------------------------------------------------------------------
extern "C" void kernel_launch(void* const* d_in, const int* in_sizes, int n_in,
                              void* d_out, int out_size, void* d_ws, size_t ws_size,
                              hipStream_t stream)
{
    const float* x        = (const float*)d_in[0];
    const float* spatial  = (const float*)d_in[1];
    const float* temporal = (const float*)d_in[2];
    const float* lw_in_b  = (const float*)d_in[4];
    const float* lw_out_b = (const float*)d_in[6];
    const float* spat_b   = (const float*)d_in[8];
    const float* temp_b   = (const float*)d_in[10];
    const float* int_in_b = (const float*)d_in[12];
    const float* int_out_b= (const float*)d_in[14];
    const float* ffn_b1   = (const float*)d_in[16];
    const float* ffn_b2   = (const float*)d_in[18];
    const float* ln1_g    = (const float*)d_in[19];
    const float* ln1_b    = (const float*)d_in[20];
    const float* ln2_g    = (const float*)d_in[21];
    const float* ln2_b    = (const float*)d_in[22];
    float* out = (float*)d_out;

    // ---- workspace layout (bytes) ----
    char* base = (char*)d_ws;
    unsigned short* qkvb = (unsigned short*)(base + 0);          // 12,582,912
    unsigned short* attnb= (unsigned short*)(base + 12582912);   //  4,194,304
    float*          x1   = (float*)(base + 16777216);            //  8,388,608 (alias part)
    unsigned short* x1b  = (unsigned short*)(base + 25165824);   //  4,194,304
    float*          x2   = (float*)(base + 29360128);            //  8,388,608
    float*          sn   = (float*)(base + 37748736);            //  8,388,608
    float*          tn   = (float*)(base + 46137344);            //  8,388,608
    unsigned short* seb  = (unsigned short*)(base + 54525952);   //  4,194,304
    unsigned short* teb  = (unsigned short*)(base + 58720256);   //  4,194,304
    unsigned short* snb  = (unsigned short*)(base + 62914560);   //  4,194,304
    unsigned short* Mtb  = (unsigned short*)(base + 67108864);   //    262,144
    float*          simb = (float*)(base + 67371008);            //     65,536
    unsigned short* Wb   = (unsigned short*)(base + 67436544);   //  1,179,648
    float*          part = x1;   // x1 dead after ffn_fused; atb runs later

    unsigned short* Wb_lwin  = Wb + 0;
    unsigned short* Wb_lwout = Wb + 49152;
    unsigned short* Wb_ffn1  = Wb + 65536;
    unsigned short* Wb_ffn2  = Wb + 131072;
    unsigned short* Wb_spat  = Wb + 196608;
    unsigned short* Wb_temp  = Wb + 212992;
    unsigned short* Wb_intin = Wb + 229376;
    unsigned short* Wb_intout= Wb + 278528;

    // --- 0. weight conversion ---
    convertW_kernel<<<1152, 256, 0, stream>>>(
        (const float*)d_in[3], (const float*)d_in[5], (const float*)d_in[15],
        (const float*)d_in[17], (const float*)d_in[7], (const float*)d_in[9],
        (const float*)d_in[11], (const float*)d_in[13], Wb);

    // --- 1. window QKV (reads x fp32 directly) -> qkvb bf16 ---
    gemm_k128<<<dim3(256, 3), 256, 0, stream>>>(
        nullptr, x, nullptr, Wb_lwin, lw_in_b, nullptr, nullptr, nullptr, nullptr,
        nullptr, qkvb, 384, 0);
    // --- 2. windowed causal attention -> attnb bf16 ---
    win_attn_kernel<<<dim3(256, 8), 64, 0, stream>>>(qkvb, attnb);
    // --- 3. out-proj + residual(x) + LN1 -> x1 fp32, x1b bf16 ---
    gemm_k128<<<dim3(256, 1), 256, 0, stream>>>(
        attnb, nullptr, nullptr, Wb_lwout, lw_out_b, x, nullptr, ln1_g, ln1_b,
        x1, x1b, 128, 2);
    // --- 4. fused FFN + LN2 -> x2 fp32 ---
    ffn_fused<<<512, 256, 0, stream>>>(
        x1b, x1, Wb_ffn1, Wb_ffn2, ffn_b1, ffn_b2, ln2_g, ln2_b, x2);
    // --- 5. se+te projections + cos-norm (one dispatch) ---
    stproj_kernel<<<dim3(256, 2), 256, 0, stream>>>(
        spatial, temporal, Wb_spat, Wb_temp, spat_b, temp_b,
        sn, tn, snb, seb, teb);
    // --- 6. M = sn^T tn per batch (split-K + transpose-reduce to bf16) ---
    atb_split_kernel<<<dim3(2, 2, 8 * ATB_SPLIT), 256, 0, stream>>>(sn, tn, part);
    atb_reduce_kernel<<<512, 256, 0, stream>>>(part, Mtb);
    // --- 7. sim = <snb@M, tn>/S via MFMA ---
    simgemm_kernel<<<256, 256, 0, stream>>>(snb, tn, Mtb, simb);
    // --- 8. interaction QKV (q from seb, k/v from teb; one dispatch) ---
    gemm_k128<<<dim3(256, 3), 256, 0, stream>>>(
        seb, nullptr, teb, Wb_intin, int_in_b, nullptr, nullptr, nullptr, nullptr,
        nullptr, qkvb, 384, 0);
    // --- 9. interaction attention -> attnb ---
    inter_attn_kernel<<<SS, 64, 0, stream>>>(qkvb, attnb);
    // --- 10. final: out = x2 + sim * (attnb @ Wout^T + bout) ---
    gemm_k128<<<dim3(256, 1), 256, 0, stream>>>(
        attnb, nullptr, nullptr, Wb_intout, int_out_b, x2, simb, nullptr, nullptr,
        out, nullptr, 128, 0);
}